// Round 1
// baseline (330.150 us; speedup 1.0000x reference)
//
#include <hip/hip_runtime.h>
#include <hip/hip_bf16.h>
#include <stdint.h>

typedef unsigned short u16;
typedef unsigned int u32;
typedef __attribute__((ext_vector_type(8))) short short8;
typedef __attribute__((ext_vector_type(4))) float f32x4;

#define T_TOK 2048
#define H_DIM 1024
#define F_DIM 4096
#define E_NUM 8
#define M_SLOT 4096
#define MAXTILES 40

__device__ __forceinline__ u16 f2bf(float f){
  union { float f; u32 u; } v; v.f = f;
  return (u16)((v.u + 0x7FFFu + ((v.u >> 16) & 1u)) >> 16);
}

__device__ __forceinline__ void gload_lds16(const void* g, void* l){
  __builtin_amdgcn_global_load_lds(
      (const __attribute__((address_space(1))) u32*)g,
      (__attribute__((address_space(3))) u32*)l, 16, 0, 0);
}

// ---------------- router: logits = x @ rw, top2, softmax ----------------
__global__ __launch_bounds__(256) void router_kernel(
    const float* __restrict__ x, const float* __restrict__ rw,
    int* __restrict__ tok_e, float* __restrict__ tok_p){
  __shared__ float wlds[E_NUM * H_DIM];   // transposed [e][h], 32KB
  int tid = threadIdx.x;
  for (int i = tid; i < H_DIM * E_NUM; i += 256){
    int h = i >> 3, e = i & 7;
    wlds[e * H_DIM + h] = rw[i];
  }
  __syncthreads();
  int wave = tid >> 6, lane = tid & 63;
  int t = blockIdx.x * 4 + wave;
  const float* xr = x + (size_t)t * H_DIM;
  float acc[E_NUM];
  #pragma unroll
  for (int e = 0; e < E_NUM; e++) acc[e] = 0.f;
  for (int i = 0; i < H_DIM / 64; i++){
    float xv = xr[lane + 64 * i];
    #pragma unroll
    for (int e = 0; e < E_NUM; e++) acc[e] += xv * wlds[e * H_DIM + lane + 64 * i];
  }
  #pragma unroll
  for (int e = 0; e < E_NUM; e++){
    float r = acc[e];
    #pragma unroll
    for (int off = 32; off; off >>= 1) r += __shfl_xor(r, off, 64);
    acc[e] = r;
  }
  if (lane == 0){
    float l0 = acc[0]; int e0 = 0;
    #pragma unroll
    for (int e = 1; e < E_NUM; e++) if (acc[e] > l0){ l0 = acc[e]; e0 = e; }
    float l1 = -INFINITY; int e1 = 0;
    #pragma unroll
    for (int e = 0; e < E_NUM; e++) if (e != e0 && acc[e] > l1){ l1 = acc[e]; e1 = e; }
    float ex = expf(l1 - l0);
    float inv = 1.f / (1.f + ex);
    tok_e[2*t] = e0; tok_e[2*t+1] = e1;
    tok_p[2*t] = inv; tok_p[2*t+1] = ex * inv;
  }
}

// ---------------- histogram: per 64-slot chunk counts per expert ----------------
__global__ void hist_kernel(const int* __restrict__ tok_e, u32* __restrict__ partial){
  int lane = threadIdx.x & 63;
  int m = blockIdx.x * 64 + lane;
  int e = tok_e[m];
  #pragma unroll
  for (int ee = 0; ee < E_NUM; ee++){
    unsigned long long mk = __ballot(e == ee);
    if (lane == ee) partial[blockIdx.x * E_NUM + ee] = (u32)__popcll(mk);
  }
}

// ---------------- scan: chunk bases + expert offsets + tile table ----------------
__global__ void scan_kernel(const u32* __restrict__ partial, u32* __restrict__ baseb,
                            int4* __restrict__ tiles, int* __restrict__ ntiles){
  int lane = threadIdx.x;  // 64 threads = 1 wave
  u32 exc[E_NUM], tot[E_NUM];
  #pragma unroll
  for (int e = 0; e < E_NUM; e++){
    u32 v = partial[lane * E_NUM + e];
    u32 own = v;
    #pragma unroll
    for (int off = 1; off < 64; off <<= 1){
      u32 tu = __shfl_up(v, off, 64);
      if (lane >= off) v += tu;
    }
    exc[e] = v - own;
    tot[e] = __shfl(v, 63, 64);
  }
  u32 offs[E_NUM + 1]; offs[0] = 0;
  #pragma unroll
  for (int e = 0; e < E_NUM; e++) offs[e+1] = offs[e] + tot[e];
  #pragma unroll
  for (int e = 0; e < E_NUM; e++) baseb[lane * E_NUM + e] = offs[e] + exc[e];
  if (lane == 0){
    int nt = 0;
    for (int e = 0; e < E_NUM; e++){
      int cnt = (int)tot[e];
      for (int r0 = 0; r0 < cnt; r0 += 128){
        tiles[nt] = make_int4((int)offs[e] + r0, min(128, cnt - r0), e, 0);
        nt++;
      }
    }
    *ntiles = nt;
  }
}

// ---------------- scatter: stable dest slot per token-copy ----------------
__global__ void scatter_kernel(const int* __restrict__ tok_e, const u32* __restrict__ baseb,
                               int* __restrict__ dest){
  int lane = threadIdx.x & 63;
  int m = blockIdx.x * 64 + lane;
  int e = tok_e[m];
  unsigned long long eq = 0;
  #pragma unroll
  for (int ee = 0; ee < E_NUM; ee++){
    unsigned long long mk = __ballot(e == ee);
    if (e == ee) eq = mk;
  }
  u32 rank = (u32)__popcll(eq & ((1ull << lane) - 1ull));
  dest[m] = (int)(baseb[blockIdx.x * E_NUM + e] + rank);
}

// ---------------- gather x rows (fp32) -> grouped bf16 A matrix ----------------
__global__ __launch_bounds__(256) void gather_kernel(const float* __restrict__ x,
                                                     const int* __restrict__ dest,
                                                     u16* __restrict__ xg){
  int m = blockIdx.x;
  int d = dest[m];
  const float4* xr = (const float4*)(x + (size_t)(m >> 1) * H_DIM);
  float4 v = xr[threadIdx.x];
  ushort4 o;
  o.x = f2bf(v.x); o.y = f2bf(v.y); o.z = f2bf(v.z); o.w = f2bf(v.w);
  ((ushort4*)(xg + (size_t)d * H_DIM))[threadIdx.x] = o;
}

// ---------------- transpose + fp32->bf16: in [E][R][C] -> out [E][C][R] ----------------
template<int R, int C>
__global__ __launch_bounds__(256) void transpose_cvt(const float* __restrict__ in,
                                                     u16* __restrict__ out){
  int e = blockIdx.z;
  const float* ip = in + (size_t)e * R * C;
  u16* op = out + (size_t)e * R * C;
  __shared__ u16 tile[64][66];
  int c0 = blockIdx.x * 64, r0 = blockIdx.y * 64;
  int tr = threadIdx.x >> 4, tc = threadIdx.x & 15;
  #pragma unroll
  for (int i = 0; i < 4; i++){
    int r = tr + i * 16;
    float4 v = *(const float4*)(ip + (size_t)(r0 + r) * C + c0 + tc * 4);
    tile[r][tc*4+0] = f2bf(v.x); tile[r][tc*4+1] = f2bf(v.y);
    tile[r][tc*4+2] = f2bf(v.z); tile[r][tc*4+3] = f2bf(v.w);
  }
  __syncthreads();
  #pragma unroll
  for (int i = 0; i < 4; i++){
    int c = tr + i * 16;  // output row within tile
    ushort4 o;
    o.x = tile[tc*4+0][c]; o.y = tile[tc*4+1][c];
    o.z = tile[tc*4+2][c]; o.w = tile[tc*4+3][c];
    *(ushort4*)(op + (size_t)(c0 + c) * R + r0 + tc * 4) = o;
  }
}

// ---------------- grouped GEMM: C[row0..row0+nr) x [col0..col0+128) ----------------
// A [*][K] bf16 row-major; Bt [E][N][K] bf16 (i.e. B transposed, K-contiguous).
template<int N, int K, bool GELU_EP>
__global__ __launch_bounds__(256) void gemm_grouped(
    const u16* __restrict__ A, const u16* __restrict__ Bt,
    const int4* __restrict__ tiles, const int* __restrict__ ntiles_p,
    float* __restrict__ outF, u16* __restrict__ outB){
  if ((int)blockIdx.y >= *ntiles_p) return;
  int4 ti = tiles[blockIdx.y];
  int row0 = ti.x, nrows = ti.y, e = ti.z;
  int col0 = blockIdx.x * 128;
  __shared__ __align__(16) u16 As[128 * 64];
  __shared__ __align__(16) u16 Bs[128 * 64];
  int tid = threadIdx.x, lane = tid & 63, wid = tid >> 6;
  int wr = wid >> 1, wc = wid & 1;
  const u16* Bte = Bt + (size_t)e * N * K;

  f32x4 acc[4][4];
  #pragma unroll
  for (int m = 0; m < 4; m++)
    #pragma unroll
    for (int n = 0; n < 4; n++) acc[m][n] = (f32x4)0.f;

  int arow = (lane >> 3);          // row within 8-row chunk
  int acol = (lane & 7) * 8;       // elem col within 64

  for (int kt = 0; kt < K / 64; kt++){
    #pragma unroll
    for (int i = 0; i < 4; i++){
      int c = wid * 4 + i;         // chunk 0..15 (8 rows each)
      const u16* ga = A + (size_t)(row0 + c * 8 + arow) * K + kt * 64 + acol;
      gload_lds16(ga, As + c * 512);
      const u16* gb = Bte + (size_t)(col0 + c * 8 + arow) * K + kt * 64 + acol;
      gload_lds16(gb, Bs + c * 512);
    }
    __syncthreads();
    #pragma unroll
    for (int kk = 0; kk < 2; kk++){
      short8 af[4], bfr[4];
      #pragma unroll
      for (int m = 0; m < 4; m++)
        af[m] = *(const short8*)(As + (wr * 64 + m * 16 + (lane & 15)) * 64 + kk * 32 + (lane >> 4) * 8);
      #pragma unroll
      for (int n = 0; n < 4; n++)
        bfr[n] = *(const short8*)(Bs + (wc * 64 + n * 16 + (lane & 15)) * 64 + kk * 32 + (lane >> 4) * 8);
      #pragma unroll
      for (int m = 0; m < 4; m++)
        #pragma unroll
        for (int n = 0; n < 4; n++)
          acc[m][n] = __builtin_amdgcn_mfma_f32_16x16x32_bf16(af[m], bfr[n], acc[m][n], 0, 0, 0);
    }
    __syncthreads();
  }

  #pragma unroll
  for (int m = 0; m < 4; m++){
    int rloc = wr * 64 + m * 16 + (lane >> 4) * 4;
    #pragma unroll
    for (int j = 0; j < 4; j++){
      int rr = rloc + j;
      if (rr < nrows){
        size_t rowg = (size_t)(row0 + rr);
        #pragma unroll
        for (int n = 0; n < 4; n++){
          int cc = col0 + wc * 64 + n * 16 + (lane & 15);
          float v = acc[m][n][j];
          if (GELU_EP){
            float g = v * 0.5f * (1.f + erff(v * 0.70710678118f));
            outF[rowg * N + cc] = g;
            outB[rowg * N + cc] = f2bf(g);
          } else {
            outF[rowg * N + cc] = v;
          }
        }
      }
    }
  }
}

// ---------------- combine: mlp[t] = p0*y[d0] + p1*y[d1] ----------------
__global__ __launch_bounds__(256) void combine_kernel(const float* __restrict__ y,
                                                      const int* __restrict__ dest,
                                                      const float* __restrict__ tok_p,
                                                      float* __restrict__ out){
  int t = blockIdx.x;
  int d0 = dest[2*t], d1 = dest[2*t+1];
  float p0 = tok_p[2*t], p1 = tok_p[2*t+1];
  const float4* y0 = (const float4*)(y + (size_t)d0 * H_DIM);
  const float4* y1 = (const float4*)(y + (size_t)d1 * H_DIM);
  float4 a = y0[threadIdx.x], b = y1[threadIdx.x];
  float4 r;
  r.x = p0*a.x + p1*b.x; r.y = p0*a.y + p1*b.y;
  r.z = p0*a.z + p1*b.z; r.w = p0*a.w + p1*b.w;
  ((float4*)(out + (size_t)t * H_DIM))[threadIdx.x] = r;
}

extern "C" void kernel_launch(void* const* d_in, const int* in_sizes, int n_in,
                              void* d_out, int out_size, void* d_ws, size_t ws_size,
                              hipStream_t stream) {
  const float* x  = (const float*)d_in[0];
  const float* rw = (const float*)d_in[1];
  const float* w1 = (const float*)d_in[2];
  const float* w2 = (const float*)d_in[3];
  float* out_mlp  = (float*)d_out;
  float* out_gelu = (float*)d_out + (size_t)T_TOK * H_DIM;

  char* ws = (char*)d_ws;
  u16* w1t   = (u16*)(ws + 0);               // [E][F][H] bf16   67108864 B
  u16* w2t   = (u16*)(ws + 67108864);        // [E][H][F] bf16   67108864 B
  u16* xg    = (u16*)(ws + 134217728);       // [M][H] bf16       8388608 B
  u16* gb    = (u16*)(ws + 142606336);       // [M][F] bf16      33554432 B
  float* y   = (float*)(ws + 176160768);     // [M][H] f32       16777216 B
  int* tok_e = (int*)(ws + 192937984);
  float* tok_p = (float*)(ws + 192954368);
  int* dest  = (int*)(ws + 192970752);
  u32* partial = (u32*)(ws + 192987136);
  u32* baseb   = (u32*)(ws + 192989184);
  int4* tiles  = (int4*)(ws + 192991232);
  int* ntiles  = (int*)(ws + 192991872);

  router_kernel<<<T_TOK/4, 256, 0, stream>>>(x, rw, tok_e, tok_p);
  hist_kernel<<<M_SLOT/64, 64, 0, stream>>>(tok_e, partial);
  scan_kernel<<<1, 64, 0, stream>>>(partial, baseb, tiles, ntiles);
  scatter_kernel<<<M_SLOT/64, 64, 0, stream>>>(tok_e, baseb, dest);
  gather_kernel<<<M_SLOT, 256, 0, stream>>>(x, dest, xg);
  transpose_cvt<H_DIM, F_DIM><<<dim3(F_DIM/64, H_DIM/64, E_NUM), 256, 0, stream>>>(w1, w1t);
  transpose_cvt<F_DIM, H_DIM><<<dim3(H_DIM/64, F_DIM/64, E_NUM), 256, 0, stream>>>(w2, w2t);
  gemm_grouped<F_DIM, H_DIM, true><<<dim3(F_DIM/128, MAXTILES), 256, 0, stream>>>(
      xg, w1t, tiles, ntiles, out_gelu, gb);
  gemm_grouped<H_DIM, F_DIM, false><<<dim3(H_DIM/128, MAXTILES), 256, 0, stream>>>(
      gb, w2t, tiles, ntiles, y, nullptr);
  combine_kernel<<<T_TOK, 256, 0, stream>>>(y, dest, tok_p, out_mlp);
}

// Round 2
// 280.982 us; speedup vs baseline: 1.1750x; 1.1750x over previous
//
#include <hip/hip_runtime.h>
#include <hip/hip_bf16.h>
#include <stdint.h>

typedef unsigned short u16;
typedef unsigned int u32;
typedef __attribute__((ext_vector_type(8))) short short8;
typedef __attribute__((ext_vector_type(4))) float f32x4;

#define T_TOK 2048
#define H_DIM 1024
#define F_DIM 4096
#define E_NUM 8
#define M_SLOT 4096
#define MAXTILES 40

__device__ __forceinline__ u16 f2bf(float f){
  union { float f; u32 u; } v; v.f = f;
  return (u16)((v.u + 0x7FFFu + ((v.u >> 16) & 1u)) >> 16);
}

__device__ __forceinline__ void gload_lds16(const void* g, void* l){
  __builtin_amdgcn_global_load_lds(
      (const __attribute__((address_space(1))) u32*)g,
      (__attribute__((address_space(3))) u32*)l, 16, 0, 0);
}

// ---------------- router: logits = x @ rw, top2, softmax ----------------
__global__ __launch_bounds__(256) void router_kernel(
    const float* __restrict__ x, const float* __restrict__ rw,
    int* __restrict__ tok_e, float* __restrict__ tok_p){
  __shared__ float wlds[E_NUM * H_DIM];   // transposed [e][h], 32KB
  int tid = threadIdx.x;
  for (int i = tid; i < H_DIM * E_NUM; i += 256){
    int h = i >> 3, e = i & 7;
    wlds[e * H_DIM + h] = rw[i];
  }
  __syncthreads();
  int wave = tid >> 6, lane = tid & 63;
  int t = blockIdx.x * 4 + wave;
  const float* xr = x + (size_t)t * H_DIM;
  float acc[E_NUM];
  #pragma unroll
  for (int e = 0; e < E_NUM; e++) acc[e] = 0.f;
  for (int i = 0; i < H_DIM / 64; i++){
    float xv = xr[lane + 64 * i];
    #pragma unroll
    for (int e = 0; e < E_NUM; e++) acc[e] += xv * wlds[e * H_DIM + lane + 64 * i];
  }
  #pragma unroll
  for (int e = 0; e < E_NUM; e++){
    float r = acc[e];
    #pragma unroll
    for (int off = 32; off; off >>= 1) r += __shfl_xor(r, off, 64);
    acc[e] = r;
  }
  if (lane == 0){
    float l0 = acc[0]; int e0 = 0;
    #pragma unroll
    for (int e = 1; e < E_NUM; e++) if (acc[e] > l0){ l0 = acc[e]; e0 = e; }
    float l1 = -INFINITY; int e1 = 0;
    #pragma unroll
    for (int e = 0; e < E_NUM; e++) if (e != e0 && acc[e] > l1){ l1 = acc[e]; e1 = e; }
    float ex = expf(l1 - l0);
    float inv = 1.f / (1.f + ex);
    tok_e[2*t] = e0; tok_e[2*t+1] = e1;
    tok_p[2*t] = inv; tok_p[2*t+1] = ex * inv;
  }
}

// ---------------- histogram: per 64-slot chunk counts per expert ----------------
__global__ void hist_kernel(const int* __restrict__ tok_e, u32* __restrict__ partial){
  int lane = threadIdx.x & 63;
  int m = blockIdx.x * 64 + lane;
  int e = tok_e[m];
  #pragma unroll
  for (int ee = 0; ee < E_NUM; ee++){
    unsigned long long mk = __ballot(e == ee);
    if (lane == ee) partial[blockIdx.x * E_NUM + ee] = (u32)__popcll(mk);
  }
}

// ---------------- scan: chunk bases + expert offsets + tile table ----------------
__global__ void scan_kernel(const u32* __restrict__ partial, u32* __restrict__ baseb,
                            int4* __restrict__ tiles, int* __restrict__ ntiles){
  int lane = threadIdx.x;  // 64 threads = 1 wave
  u32 exc[E_NUM], tot[E_NUM];
  #pragma unroll
  for (int e = 0; e < E_NUM; e++){
    u32 v = partial[lane * E_NUM + e];
    u32 own = v;
    #pragma unroll
    for (int off = 1; off < 64; off <<= 1){
      u32 tu = __shfl_up(v, off, 64);
      if (lane >= off) v += tu;
    }
    exc[e] = v - own;
    tot[e] = __shfl(v, 63, 64);
  }
  u32 offs[E_NUM + 1]; offs[0] = 0;
  #pragma unroll
  for (int e = 0; e < E_NUM; e++) offs[e+1] = offs[e] + tot[e];
  #pragma unroll
  for (int e = 0; e < E_NUM; e++) baseb[lane * E_NUM + e] = offs[e] + exc[e];
  if (lane == 0){
    int nt = 0;
    for (int e = 0; e < E_NUM; e++){
      int cnt = (int)tot[e];
      for (int r0 = 0; r0 < cnt; r0 += 128){
        tiles[nt] = make_int4((int)offs[e] + r0, min(128, cnt - r0), e, 0);
        nt++;
      }
    }
    *ntiles = nt;
  }
}

// ---------------- scatter: stable dest slot per token-copy ----------------
__global__ void scatter_kernel(const int* __restrict__ tok_e, const u32* __restrict__ baseb,
                               int* __restrict__ dest){
  int lane = threadIdx.x & 63;
  int m = blockIdx.x * 64 + lane;
  int e = tok_e[m];
  unsigned long long eq = 0;
  #pragma unroll
  for (int ee = 0; ee < E_NUM; ee++){
    unsigned long long mk = __ballot(e == ee);
    if (e == ee) eq = mk;
  }
  u32 rank = (u32)__popcll(eq & ((1ull << lane) - 1ull));
  dest[m] = (int)(baseb[blockIdx.x * E_NUM + e] + rank);
}

// ---------------- gather x rows (fp32) -> grouped bf16 A matrix ----------------
__global__ __launch_bounds__(256) void gather_kernel(const float* __restrict__ x,
                                                     const int* __restrict__ dest,
                                                     u16* __restrict__ xg){
  int m = blockIdx.x;
  int d = dest[m];
  const float4* xr = (const float4*)(x + (size_t)(m >> 1) * H_DIM);
  float4 v = xr[threadIdx.x];
  ushort4 o;
  o.x = f2bf(v.x); o.y = f2bf(v.y); o.z = f2bf(v.z); o.w = f2bf(v.w);
  ((ushort4*)(xg + (size_t)d * H_DIM))[threadIdx.x] = o;
}

// ---------------- transpose + fp32->bf16: in [E][R][C] -> out [E][C][R] ----------------
template<int R, int C>
__global__ __launch_bounds__(256) void transpose_cvt(const float* __restrict__ in,
                                                     u16* __restrict__ out){
  int e = blockIdx.z;
  const float* ip = in + (size_t)e * R * C;
  u16* op = out + (size_t)e * R * C;
  __shared__ u16 tile[64][66];
  int c0 = blockIdx.x * 64, r0 = blockIdx.y * 64;
  int tr = threadIdx.x >> 4, tc = threadIdx.x & 15;
  #pragma unroll
  for (int i = 0; i < 4; i++){
    int r = tr + i * 16;
    float4 v = *(const float4*)(ip + (size_t)(r0 + r) * C + c0 + tc * 4);
    tile[r][tc*4+0] = f2bf(v.x); tile[r][tc*4+1] = f2bf(v.y);
    tile[r][tc*4+2] = f2bf(v.z); tile[r][tc*4+3] = f2bf(v.w);
  }
  __syncthreads();
  #pragma unroll
  for (int i = 0; i < 4; i++){
    int c = tr + i * 16;  // output row within tile
    ushort4 o;
    o.x = tile[tc*4+0][c]; o.y = tile[tc*4+1][c];
    o.z = tile[tc*4+2][c]; o.w = tile[tc*4+3][c];
    *(ushort4*)(op + (size_t)(c0 + c) * R + r0 + tc * 4) = o;
  }
}

// ---------------- grouped GEMM, 2-phase double-buffered prefetch ----------------
// A [*][K] bf16 row-major; Bt [E][N][K] bf16 (K-contiguous).
// BM=128 rows, BN cols per tile, BK=64. 4 waves.
template<int BN, int N, int K, bool GELU_EP>
__global__ __launch_bounds__(256) void gemm_grouped(
    const u16* __restrict__ A, const u16* __restrict__ Bt,
    const int4* __restrict__ tiles, const int* __restrict__ ntiles_p,
    float* __restrict__ outF, u16* __restrict__ outB){
  constexpr int BM = 128, BK = 64;
  constexpr int NT = K / BK;                  // even (16 or 64)
  constexpr int WR = (BN == 128) ? 2 : 4;     // wave grid rows
  constexpr int WC = (BN == 128) ? 2 : 1;     // wave grid cols
  constexpr int MM = BM / (WR * 16);          // acc row frags (4 or 2)
  constexpr int NN = BN / (WC * 16);          // acc col frags (4)
  constexpr int ACH = BM / 8;                 // A chunks (8 rows each)
  constexpr int BCH = BN / 8;                 // B chunks
  constexpr int PW = (ACH + BCH) / 4;         // chunks per wave

  if ((int)blockIdx.y >= *ntiles_p) return;
  int4 ti = tiles[blockIdx.y];
  int row0 = ti.x, nrows = ti.y, e = ti.z;
  int col0 = blockIdx.x * BN;

  // statically named double buffers (keeps all LDS refs compile-time disjoint)
  __shared__ __align__(16) u16 As0[BM * BK], As1[BM * BK];
  __shared__ __align__(16) u16 Bs0[BN * BK], Bs1[BN * BK];

  int tid = threadIdx.x, lane = tid & 63, wid = tid >> 6;
  int wr = wid / WC, wc = wid % WC;
  const u16* Bte = Bt + (size_t)e * N * K;

  f32x4 acc[MM][NN];
  #pragma unroll
  for (int m = 0; m < MM; m++)
    #pragma unroll
    for (int n = 0; n < NN; n++) acc[m][n] = (f32x4)0.f;

  int arow = (lane >> 3);          // row within 8-row chunk
  int acol = (lane & 7) * 8;       // elem col within BK

  auto stage = [&](u16* As, u16* Bs, int kt) {
    #pragma unroll
    for (int i = 0; i < PW; i++){
      int c = wid * PW + i;        // wave-uniform chunk id
      if (c < ACH){
        const u16* ga = A + (size_t)(row0 + c * 8 + arow) * K + kt * BK + acol;
        gload_lds16(ga, As + c * 512);
      } else {
        int cb = c - ACH;
        const u16* gb = Bte + (size_t)(col0 + cb * 8 + arow) * K + kt * BK + acol;
        gload_lds16(gb, Bs + cb * 512);
      }
    }
  };

  auto compute = [&](const u16* As, const u16* Bs) {
    #pragma unroll
    for (int kk = 0; kk < 2; kk++){
      short8 af[MM], bfr[NN];
      #pragma unroll
      for (int m = 0; m < MM; m++)
        af[m] = *(const short8*)(As + (wr * (MM * 16) + m * 16 + (lane & 15)) * BK + kk * 32 + (lane >> 4) * 8);
      #pragma unroll
      for (int n = 0; n < NN; n++)
        bfr[n] = *(const short8*)(Bs + (wc * (NN * 16) + n * 16 + (lane & 15)) * BK + kk * 32 + (lane >> 4) * 8);
      #pragma unroll
      for (int m = 0; m < MM; m++)
        #pragma unroll
        for (int n = 0; n < NN; n++)
          acc[m][n] = __builtin_amdgcn_mfma_f32_16x16x32_bf16(af[m], bfr[n], acc[m][n], 0, 0, 0);
    }
  };

  stage(As0, Bs0, 0);
  __syncthreads();                          // implicit vmcnt(0): tile 0 landed

  for (int kt = 0; kt < NT; kt += 2){
    stage(As1, Bs1, kt + 1);                // prefetch next (always valid: kt+1 <= NT-1)
    compute(As0, Bs0);
    __syncthreads();                        // drain overlaps with compute above
    if (kt + 2 < NT) stage(As0, Bs0, kt + 2);
    compute(As1, Bs1);
    __syncthreads();
  }

  #pragma unroll
  for (int m = 0; m < MM; m++){
    int rloc = wr * (MM * 16) + m * 16 + (lane >> 4) * 4;
    #pragma unroll
    for (int j = 0; j < 4; j++){
      int rr = rloc + j;
      if (rr < nrows){
        size_t rowg = (size_t)(row0 + rr);
        #pragma unroll
        for (int n = 0; n < NN; n++){
          int cc = col0 + wc * (NN * 16) + n * 16 + (lane & 15);
          float v = acc[m][n][j];
          if (GELU_EP){
            float g = v * 0.5f * (1.f + erff(v * 0.70710678118f));
            outF[rowg * N + cc] = g;
            outB[rowg * N + cc] = f2bf(g);
          } else {
            outF[rowg * N + cc] = v;
          }
        }
      }
    }
  }
}

// ---------------- combine: mlp[t] = p0*y[d0] + p1*y[d1] ----------------
__global__ __launch_bounds__(256) void combine_kernel(const float* __restrict__ y,
                                                      const int* __restrict__ dest,
                                                      const float* __restrict__ tok_p,
                                                      float* __restrict__ out){
  int t = blockIdx.x;
  int d0 = dest[2*t], d1 = dest[2*t+1];
  float p0 = tok_p[2*t], p1 = tok_p[2*t+1];
  const float4* y0 = (const float4*)(y + (size_t)d0 * H_DIM);
  const float4* y1 = (const float4*)(y + (size_t)d1 * H_DIM);
  float4 a = y0[threadIdx.x], b = y1[threadIdx.x];
  float4 r;
  r.x = p0*a.x + p1*b.x; r.y = p0*a.y + p1*b.y;
  r.z = p0*a.z + p1*b.z; r.w = p0*a.w + p1*b.w;
  ((float4*)(out + (size_t)t * H_DIM))[threadIdx.x] = r;
}

extern "C" void kernel_launch(void* const* d_in, const int* in_sizes, int n_in,
                              void* d_out, int out_size, void* d_ws, size_t ws_size,
                              hipStream_t stream) {
  const float* x  = (const float*)d_in[0];
  const float* rw = (const float*)d_in[1];
  const float* w1 = (const float*)d_in[2];
  const float* w2 = (const float*)d_in[3];
  float* out_mlp  = (float*)d_out;
  float* out_gelu = (float*)d_out + (size_t)T_TOK * H_DIM;

  char* ws = (char*)d_ws;
  u16* w1t   = (u16*)(ws + 0);               // [E][F][H] bf16   67108864 B
  u16* w2t   = (u16*)(ws + 67108864);        // [E][H][F] bf16   67108864 B
  u16* xg    = (u16*)(ws + 134217728);       // [M][H] bf16       8388608 B
  u16* gb    = (u16*)(ws + 142606336);       // [M][F] bf16      33554432 B
  float* y   = (float*)(ws + 176160768);     // [M][H] f32       16777216 B
  int* tok_e = (int*)(ws + 192937984);
  float* tok_p = (float*)(ws + 192954368);
  int* dest  = (int*)(ws + 192970752);
  u32* partial = (u32*)(ws + 192987136);
  u32* baseb   = (u32*)(ws + 192989184);
  int4* tiles  = (int4*)(ws + 192991232);
  int* ntiles  = (int*)(ws + 192991872);

  router_kernel<<<T_TOK/4, 256, 0, stream>>>(x, rw, tok_e, tok_p);
  hist_kernel<<<M_SLOT/64, 64, 0, stream>>>(tok_e, partial);
  scan_kernel<<<1, 64, 0, stream>>>(partial, baseb, tiles, ntiles);
  scatter_kernel<<<M_SLOT/64, 64, 0, stream>>>(tok_e, baseb, dest);
  gather_kernel<<<M_SLOT, 256, 0, stream>>>(x, dest, xg);
  transpose_cvt<H_DIM, F_DIM><<<dim3(F_DIM/64, H_DIM/64, E_NUM), 256, 0, stream>>>(w1, w1t);
  transpose_cvt<F_DIM, H_DIM><<<dim3(H_DIM/64, F_DIM/64, E_NUM), 256, 0, stream>>>(w2, w2t);
  gemm_grouped<128, F_DIM, H_DIM, true><<<dim3(F_DIM/128, MAXTILES), 256, 0, stream>>>(
      xg, w1t, tiles, ntiles, out_gelu, gb);
  gemm_grouped<64, H_DIM, F_DIM, false><<<dim3(H_DIM/64, MAXTILES), 256, 0, stream>>>(
      gb, w2t, tiles, ntiles, y, nullptr);
  combine_kernel<<<T_TOK, 256, 0, stream>>>(y, dest, tok_p, out_mlp);
}

// Round 4
// 268.213 us; speedup vs baseline: 1.2309x; 1.0476x over previous
//
#include <hip/hip_runtime.h>
#include <hip/hip_bf16.h>
#include <stdint.h>

typedef unsigned short u16;
typedef unsigned int u32;
typedef __attribute__((ext_vector_type(8))) short short8;
typedef __attribute__((ext_vector_type(4))) float f32x4;

#define T_TOK 2048
#define H_DIM 1024
#define F_DIM 4096
#define E_NUM 8
#define M_SLOT 4096
#define MAXTILES 24
#define KSPLIT 4

__device__ __forceinline__ u16 f2bf(float f){
  union { float f; u32 u; } v; v.f = f;
  return (u16)((v.u + 0x7FFFu + ((v.u >> 16) & 1u)) >> 16);
}

__device__ __forceinline__ void gload_lds16(const void* g, void* l){
  __builtin_amdgcn_global_load_lds(
      (const __attribute__((address_space(1))) u32*)g,
      (__attribute__((address_space(3))) u32*)l, 16, 0, 0);
}

#define SCHED0() __builtin_amdgcn_sched_barrier(0)
#define BARRIER() do { SCHED0(); __builtin_amdgcn_s_barrier(); SCHED0(); } while(0)
#define VMC4() asm volatile("s_waitcnt vmcnt(4)" ::: "memory")
#define VMC2() asm volatile("s_waitcnt vmcnt(2)" ::: "memory")
#define VMC0() asm volatile("s_waitcnt vmcnt(0)" ::: "memory")

// ---------------- router: logits = x @ rw, top2, softmax ----------------
__global__ __launch_bounds__(256) void router_kernel(
    const float* __restrict__ x, const float* __restrict__ rw,
    int* __restrict__ tok_e, float* __restrict__ tok_p){
  __shared__ float wlds[E_NUM * H_DIM];
  int tid = threadIdx.x;
  for (int i = tid; i < H_DIM * E_NUM; i += 256){
    int h = i >> 3, e = i & 7;
    wlds[e * H_DIM + h] = rw[i];
  }
  __syncthreads();
  int wave = tid >> 6, lane = tid & 63;
  int t = blockIdx.x * 4 + wave;
  const float* xr = x + (size_t)t * H_DIM;
  float acc[E_NUM];
  #pragma unroll
  for (int e = 0; e < E_NUM; e++) acc[e] = 0.f;
  for (int i = 0; i < H_DIM / 64; i++){
    float xv = xr[lane + 64 * i];
    #pragma unroll
    for (int e = 0; e < E_NUM; e++) acc[e] += xv * wlds[e * H_DIM + lane + 64 * i];
  }
  #pragma unroll
  for (int e = 0; e < E_NUM; e++){
    float r = acc[e];
    #pragma unroll
    for (int off = 32; off; off >>= 1) r += __shfl_xor(r, off, 64);
    acc[e] = r;
  }
  if (lane == 0){
    float l0 = acc[0]; int e0 = 0;
    #pragma unroll
    for (int e = 1; e < E_NUM; e++) if (acc[e] > l0){ l0 = acc[e]; e0 = e; }
    float l1 = -INFINITY; int e1 = 0;
    #pragma unroll
    for (int e = 0; e < E_NUM; e++) if (e != e0 && acc[e] > l1){ l1 = acc[e]; e1 = e; }
    float ex = expf(l1 - l0);
    float inv = 1.f / (1.f + ex);
    tok_e[2*t] = e0; tok_e[2*t+1] = e1;
    tok_p[2*t] = inv; tok_p[2*t+1] = ex * inv;
  }
}

// ---------------- histogram ----------------
__global__ void hist_kernel(const int* __restrict__ tok_e, u32* __restrict__ partial){
  int lane = threadIdx.x & 63;
  int m = blockIdx.x * 64 + lane;
  int e = tok_e[m];
  #pragma unroll
  for (int ee = 0; ee < E_NUM; ee++){
    unsigned long long mk = __ballot(e == ee);
    if (lane == ee) partial[blockIdx.x * E_NUM + ee] = (u32)__popcll(mk);
  }
}

// ---------------- scan + tile table (256-row tiles) ----------------
__global__ void scan_kernel(const u32* __restrict__ partial, u32* __restrict__ baseb,
                            int4* __restrict__ tiles, int* __restrict__ ntiles){
  int lane = threadIdx.x;  // 64 threads
  u32 exc[E_NUM], tot[E_NUM];
  #pragma unroll
  for (int e = 0; e < E_NUM; e++){
    u32 v = partial[lane * E_NUM + e];
    u32 own = v;
    #pragma unroll
    for (int off = 1; off < 64; off <<= 1){
      u32 tu = __shfl_up(v, off, 64);
      if (lane >= off) v += tu;
    }
    exc[e] = v - own;
    tot[e] = __shfl(v, 63, 64);
  }
  u32 offs[E_NUM + 1]; offs[0] = 0;
  #pragma unroll
  for (int e = 0; e < E_NUM; e++) offs[e+1] = offs[e] + tot[e];
  #pragma unroll
  for (int e = 0; e < E_NUM; e++) baseb[lane * E_NUM + e] = offs[e] + exc[e];
  if (lane == 0){
    int nt = 0;
    for (int e = 0; e < E_NUM; e++){
      int cnt = (int)tot[e];
      for (int r0 = 0; r0 < cnt; r0 += 256){
        tiles[nt] = make_int4((int)offs[e] + r0, min(256, cnt - r0), e, 0);
        nt++;
      }
    }
    *ntiles = nt;
  }
}

// ---------------- scatter ----------------
__global__ void scatter_kernel(const int* __restrict__ tok_e, const u32* __restrict__ baseb,
                               int* __restrict__ dest){
  int lane = threadIdx.x & 63;
  int m = blockIdx.x * 64 + lane;
  int e = tok_e[m];
  unsigned long long eq = 0;
  #pragma unroll
  for (int ee = 0; ee < E_NUM; ee++){
    unsigned long long mk = __ballot(e == ee);
    if (e == ee) eq = mk;
  }
  u32 rank = (u32)__popcll(eq & ((1ull << lane) - 1ull));
  dest[m] = (int)(baseb[blockIdx.x * E_NUM + e] + rank);
}

// ---------------- gather x rows -> grouped bf16 ----------------
__global__ __launch_bounds__(256) void gather_kernel(const float* __restrict__ x,
                                                     const int* __restrict__ dest,
                                                     u16* __restrict__ xg){
  int m = blockIdx.x;
  int d = dest[m];
  const float4* xr = (const float4*)(x + (size_t)(m >> 1) * H_DIM);
  float4 v = xr[threadIdx.x];
  ushort4 o;
  o.x = f2bf(v.x); o.y = f2bf(v.y); o.z = f2bf(v.z); o.w = f2bf(v.w);
  ((ushort4*)(xg + (size_t)d * H_DIM))[threadIdx.x] = o;
}

// ---------------- transpose + fp32->bf16: [E][R][C] -> [E][C][R] ----------------
template<int R, int C>
__global__ __launch_bounds__(256) void transpose_cvt(const float* __restrict__ in,
                                                     u16* __restrict__ out){
  int e = blockIdx.z;
  const float* ip = in + (size_t)e * R * C;
  u16* op = out + (size_t)e * R * C;
  __shared__ u16 tile[64][66];
  int c0 = blockIdx.x * 64, r0 = blockIdx.y * 64;
  int tr = threadIdx.x >> 4, tc = threadIdx.x & 15;
  #pragma unroll
  for (int i = 0; i < 4; i++){
    int r = tr + i * 16;
    float4 v = *(const float4*)(ip + (size_t)(r0 + r) * C + c0 + tc * 4);
    tile[r][tc*4+0] = f2bf(v.x); tile[r][tc*4+1] = f2bf(v.y);
    tile[r][tc*4+2] = f2bf(v.z); tile[r][tc*4+3] = f2bf(v.w);
  }
  __syncthreads();
  #pragma unroll
  for (int i = 0; i < 4; i++){
    int c = tr + i * 16;
    ushort4 o;
    o.x = tile[tc*4+0][c]; o.y = tile[tc*4+1][c];
    o.z = tile[tc*4+2][c]; o.w = tile[tc*4+3][c];
    *(ushort4*)(op + (size_t)(c0 + c) * R + r0 + tc * 4) = o;
  }
}

// ---------------- grouped GEMM, 256x256 tile, 4-phase/K-tile, counted vmcnt ----
// A [*][KSTRIDE] bf16; Bt [E][N][KSTRIDE] bf16. K-chunk = 1024 (NT=16 tiles of 64).
// 8 waves (2 wrow x 4 wcol). LDS halves: 0=A rows0-127, 1=A rows128-255,
// 2=B cols0-127, 3=B cols128-255; each [128 rows][64 u16], XOR-swizzled
// (row&7)<<4 on byte offset (write side: inverse-swizzled global src, rule #21).
//
// Sync invariant (the round-3 bug): a wave's counted vmcnt only covers ITS OWN
// global_load_lds; halves are staged by all 8 waves; so every ds_read of a half
// must be preceded by {each wave: vmcnt covering that half} -> s_barrier.
// Phase layout: frd(cur) | stage(next) | BARRIER | MFMA | vmcnt(counted) | BARRIER.
// Issue order per tile: A0@P0, B0@P1, B1@P2, A1@P3 (2 loads each).
// Steady state waits: P0 end vmcnt(4) [B1 landed], P1 end vmcnt(4) [A1 landed],
// P2 end none, P3 end vmcnt(4) [next A0,B0 landed]. Last tile: 2/0/none/none.
template<int N, int KSTRIDE, bool GELU_EP>
__global__ __launch_bounds__(512, 2) void gemm8(
    const u16* __restrict__ A, const u16* __restrict__ Bt,
    const int4* __restrict__ tiles, const int* __restrict__ ntiles_p,
    float* __restrict__ outF, u16* __restrict__ outB, size_t zstride){
  constexpr int NT = 16;
  if ((int)blockIdx.y >= *ntiles_p) return;
  int4 ti = tiles[blockIdx.y];
  int row0 = ti.x, nrows = ti.y, e = ti.z;
  int col0 = blockIdx.x * 256;
  int z = blockIdx.z;
  size_t kofs = (size_t)z * 1024;
  const u16* Be = Bt + (size_t)e * N * KSTRIDE;
  float* outFz = outF + (size_t)z * zstride;

  __shared__ __align__(16) u16 lds[2][4][128 * 64];

  int tid = threadIdx.x, lane = tid & 63, wid = tid >> 6;
  int wrow = wid >> 2, wcol = wid & 3;

  auto stg = [&](int p, int half, int kt){
    const u16* gb_; int rb;
    if (half < 2){ gb_ = A;  rb = row0 + half * 128; }
    else         { gb_ = Be; rb = col0 + (half - 2) * 128; }
    #pragma unroll
    for (int j = 0; j < 2; j++){
      int crow = j * 64 + wid * 8 + (lane >> 3);
      int cb = ((lane & 7) * 16) ^ ((lane >> 3) << 4);
      const char* g = (const char*)(gb_ + (size_t)(rb + crow) * KSTRIDE + kofs + kt * 64) + cb;
      u16* l = (u16*)&lds[p][half][0] + (size_t)(j * 512 + wid * 64) * 8;
      gload_lds16(g, l);
    }
  };

  auto frd = [&](int p, int half, int rb16, int kk)->short8{
    int row = rb16 + (lane & 15);            // rb16 % 16 == 0, so row&7 == lane&7
    int byte_ = row * 128 + ((kk * 64 + (lane >> 4) * 16) ^ ((lane & 7) << 4));
    return *(const short8*)((const char*)&lds[p][half][0] + byte_);
  };

  f32x4 acc[8][4];
  #pragma unroll
  for (int m = 0; m < 8; m++)
    #pragma unroll
    for (int n = 0; n < 4; n++) acc[m][n] = (f32x4)0.f;

  short8 a[4][2], b[4][2];

  // prologue: tile 0, issue order A0,B0,B1,A1 (8 loads in flight)
  stg(0, 0, 0); stg(0, 2, 0); stg(0, 3, 0); stg(0, 1, 0);
  VMC4();                                   // own A0,B0 landed
  BARRIER();                                // publish across waves

  for (int kt = 0; kt < NT; kt++){
    int p = kt & 1, q = p ^ 1;
    bool pre = (kt + 1 < NT);
    // ---- P0: read A0,B0 (valid per prior vmcnt+barrier)
    #pragma unroll
    for (int m = 0; m < 4; m++)
      #pragma unroll
      for (int kk = 0; kk < 2; kk++) a[m][kk] = frd(p, 0, wrow * 16 + m * 32, kk);
    #pragma unroll
    for (int n = 0; n < 2; n++)
      #pragma unroll
      for (int kk = 0; kk < 2; kk++) b[n][kk] = frd(p, 2, wcol * 16 + n * 64, kk);
    if (pre) stg(q, 0, kt + 1);
    BARRIER();
    __builtin_amdgcn_s_setprio(1);
    #pragma unroll
    for (int m = 0; m < 4; m++)
      #pragma unroll
      for (int n = 0; n < 2; n++)
        #pragma unroll
        for (int kk = 0; kk < 2; kk++)
          acc[m][n] = __builtin_amdgcn_mfma_f32_16x16x32_bf16(a[m][kk], b[n][kk], acc[m][n], 0, 0, 0);
    __builtin_amdgcn_s_setprio(0);
    if (pre) { VMC4(); } else { VMC2(); }   // B1 of current tile landed
    BARRIER();
    // ---- P1: read B1
    #pragma unroll
    for (int n = 2; n < 4; n++)
      #pragma unroll
      for (int kk = 0; kk < 2; kk++) b[n][kk] = frd(p, 3, wcol * 16 + (n - 2) * 64, kk);
    if (pre) stg(q, 2, kt + 1);
    BARRIER();
    __builtin_amdgcn_s_setprio(1);
    #pragma unroll
    for (int m = 0; m < 4; m++)
      #pragma unroll
      for (int n = 2; n < 4; n++)
        #pragma unroll
        for (int kk = 0; kk < 2; kk++)
          acc[m][n] = __builtin_amdgcn_mfma_f32_16x16x32_bf16(a[m][kk], b[n][kk], acc[m][n], 0, 0, 0);
    __builtin_amdgcn_s_setprio(0);
    if (pre) { VMC4(); } else { VMC0(); }   // A1 of current tile landed
    BARRIER();
    // ---- P2: read A1
    #pragma unroll
    for (int m = 0; m < 4; m++)
      #pragma unroll
      for (int kk = 0; kk < 2; kk++) a[m][kk] = frd(p, 1, wrow * 16 + m * 32, kk);
    if (pre) stg(q, 3, kt + 1);
    BARRIER();
    __builtin_amdgcn_s_setprio(1);
    #pragma unroll
    for (int m = 0; m < 4; m++)
      #pragma unroll
      for (int n = 2; n < 4; n++)
        #pragma unroll
        for (int kk = 0; kk < 2; kk++)
          acc[m + 4][n] = __builtin_amdgcn_mfma_f32_16x16x32_bf16(a[m][kk], b[n][kk], acc[m + 4][n], 0, 0, 0);
    __builtin_amdgcn_s_setprio(0);
    BARRIER();                              // B0 re-read needs no new wait
    // ---- P3: read B0 again
    #pragma unroll
    for (int n = 0; n < 2; n++)
      #pragma unroll
      for (int kk = 0; kk < 2; kk++) b[n][kk] = frd(p, 2, wcol * 16 + n * 64, kk);
    if (pre) stg(q, 1, kt + 1);
    BARRIER();
    __builtin_amdgcn_s_setprio(1);
    #pragma unroll
    for (int m = 0; m < 4; m++)
      #pragma unroll
      for (int n = 0; n < 2; n++)
        #pragma unroll
        for (int kk = 0; kk < 2; kk++)
          acc[m + 4][n] = __builtin_amdgcn_mfma_f32_16x16x32_bf16(a[m][kk], b[n][kk], acc[m + 4][n], 0, 0, 0);
    __builtin_amdgcn_s_setprio(0);
    if (pre) { VMC4(); }                    // next tile's A0,B0 landed
    BARRIER();
  }

  // epilogue
  #pragma unroll
  for (int m = 0; m < 8; m++){
    int rloc = ((m < 4) ? 0 : 128) + wrow * 16 + (m & 3) * 32 + (lane >> 4) * 4;
    #pragma unroll
    for (int j = 0; j < 4; j++){
      int rr = rloc + j;
      if (rr < nrows){
        size_t rowg = (size_t)(row0 + rr);
        #pragma unroll
        for (int n = 0; n < 4; n++){
          int cc = col0 + ((n < 2) ? 0 : 128) + wcol * 16 + (n & 1) * 64 + (lane & 15);
          float v = acc[m][n][j];
          if (GELU_EP){
            float g = v * 0.5f * (1.f + erff(v * 0.70710678118f));
            outFz[rowg * N + cc] = g;
            outB[rowg * N + cc] = f2bf(g);
          } else {
            outFz[rowg * N + cc] = v;
          }
        }
      }
    }
  }
}

// ---------------- combine: sum 4 split-K partials, weighted ----------------
__global__ __launch_bounds__(256) void combine_kernel(const float* __restrict__ yp,
                                                      const int* __restrict__ dest,
                                                      const float* __restrict__ tok_p,
                                                      float* __restrict__ out){
  int t = blockIdx.x;
  int d0 = dest[2*t], d1 = dest[2*t+1];
  float p0 = tok_p[2*t], p1 = tok_p[2*t+1];
  float4 r; r.x = 0.f; r.y = 0.f; r.z = 0.f; r.w = 0.f;
  #pragma unroll
  for (int s = 0; s < KSPLIT; s++){
    float4 a = ((const float4*)(yp + ((size_t)s * M_SLOT + d0) * H_DIM))[threadIdx.x];
    float4 b = ((const float4*)(yp + ((size_t)s * M_SLOT + d1) * H_DIM))[threadIdx.x];
    r.x += p0*a.x + p1*b.x; r.y += p0*a.y + p1*b.y;
    r.z += p0*a.z + p1*b.z; r.w += p0*a.w + p1*b.w;
  }
  ((float4*)(out + (size_t)t * H_DIM))[threadIdx.x] = r;
}

extern "C" void kernel_launch(void* const* d_in, const int* in_sizes, int n_in,
                              void* d_out, int out_size, void* d_ws, size_t ws_size,
                              hipStream_t stream) {
  const float* x  = (const float*)d_in[0];
  const float* rw = (const float*)d_in[1];
  const float* w1 = (const float*)d_in[2];
  const float* w2 = (const float*)d_in[3];
  float* out_mlp  = (float*)d_out;
  float* out_gelu = (float*)d_out + (size_t)T_TOK * H_DIM;

  char* ws = (char*)d_ws;
  // layout (ypart aliases w1t: w1t dead after GEMM1, ypart written by GEMM2)
  u16*   w1t   = (u16*)(ws + 0);                 // [E][F][H] bf16, 64 MB
  float* ypart = (float*)(ws + 0);               // [4][M][H] f32,  64 MB (alias)
  u16*   w2t   = (u16*)(ws + 67108864);          // [E][H][F] bf16, 64 MB
  u16*   xg    = (u16*)(ws + 134217728);         // [M+256][H] bf16, 8.9 MB
  u16*   gb    = (u16*)(ws + 143130624);         // [M+256][F] bf16, 35.7 MB
  char*  small = ws + 178782208;
  int*   tok_e = (int*)(small);
  float* tok_p = (float*)(small + 16384);
  int*   dest  = (int*)(small + 32768);
  u32*   partial = (u32*)(small + 49152);
  u32*   baseb   = (u32*)(small + 51200);
  int4*  tiles   = (int4*)(small + 53248);
  int*   ntiles  = (int*)(small + 53888);

  router_kernel<<<T_TOK/4, 256, 0, stream>>>(x, rw, tok_e, tok_p);
  hist_kernel<<<M_SLOT/64, 64, 0, stream>>>(tok_e, partial);
  scan_kernel<<<1, 64, 0, stream>>>(partial, baseb, tiles, ntiles);
  scatter_kernel<<<M_SLOT/64, 64, 0, stream>>>(tok_e, baseb, dest);
  gather_kernel<<<M_SLOT, 256, 0, stream>>>(x, dest, xg);
  transpose_cvt<H_DIM, F_DIM><<<dim3(F_DIM/64, H_DIM/64, E_NUM), 256, 0, stream>>>(w1, w1t);
  transpose_cvt<F_DIM, H_DIM><<<dim3(H_DIM/64, F_DIM/64, E_NUM), 256, 0, stream>>>(w2, w2t);
  gemm8<F_DIM, H_DIM, true><<<dim3(F_DIM/256, MAXTILES, 1), 512, 0, stream>>>(
      xg, w1t, tiles, ntiles, out_gelu, gb, 0);
  gemm8<H_DIM, F_DIM, false><<<dim3(H_DIM/256, MAXTILES, KSPLIT), 512, 0, stream>>>(
      gb, w2t, tiles, ntiles, ypart, nullptr, (size_t)M_SLOT * H_DIM);
  combine_kernel<<<T_TOK, 256, 0, stream>>>(ypart, dest, tok_p, out_mlp);
}

// Round 5
// 254.018 us; speedup vs baseline: 1.2997x; 1.0559x over previous
//
#include <hip/hip_runtime.h>
#include <hip/hip_bf16.h>
#include <stdint.h>

typedef unsigned short u16;
typedef unsigned int u32;
typedef __attribute__((ext_vector_type(8))) short short8;
typedef __attribute__((ext_vector_type(4))) float f32x4;

#define T_TOK 2048
#define H_DIM 1024
#define F_DIM 4096
#define E_NUM 8
#define M_SLOT 4096
#define MAXTILES 40
#define KSPLIT 2

__device__ __forceinline__ u16 f2bf(float f){
  union { float f; u32 u; } v; v.f = f;
  return (u16)((v.u + 0x7FFFu + ((v.u >> 16) & 1u)) >> 16);
}

__device__ __forceinline__ void gload_lds16(const void* g, void* l){
  __builtin_amdgcn_global_load_lds(
      (const __attribute__((address_space(1))) u32*)g,
      (__attribute__((address_space(3))) u32*)l, 16, 0, 0);
}

// ---------------- router: logits = x @ rw, top2, softmax ----------------
__global__ __launch_bounds__(256) void router_kernel(
    const float* __restrict__ x, const float* __restrict__ rw,
    int* __restrict__ tok_e, float* __restrict__ tok_p){
  __shared__ float wlds[E_NUM * H_DIM];
  int tid = threadIdx.x;
  for (int i = tid; i < H_DIM * E_NUM; i += 256){
    int h = i >> 3, e = i & 7;
    wlds[e * H_DIM + h] = rw[i];
  }
  __syncthreads();
  int wave = tid >> 6, lane = tid & 63;
  int t = blockIdx.x * 4 + wave;
  const float* xr = x + (size_t)t * H_DIM;
  float acc[E_NUM];
  #pragma unroll
  for (int e = 0; e < E_NUM; e++) acc[e] = 0.f;
  for (int i = 0; i < H_DIM / 64; i++){
    float xv = xr[lane + 64 * i];
    #pragma unroll
    for (int e = 0; e < E_NUM; e++) acc[e] += xv * wlds[e * H_DIM + lane + 64 * i];
  }
  #pragma unroll
  for (int e = 0; e < E_NUM; e++){
    float r = acc[e];
    #pragma unroll
    for (int off = 32; off; off >>= 1) r += __shfl_xor(r, off, 64);
    acc[e] = r;
  }
  if (lane == 0){
    float l0 = acc[0]; int e0 = 0;
    #pragma unroll
    for (int e = 1; e < E_NUM; e++) if (acc[e] > l0){ l0 = acc[e]; e0 = e; }
    float l1 = -INFINITY; int e1 = 0;
    #pragma unroll
    for (int e = 0; e < E_NUM; e++) if (e != e0 && acc[e] > l1){ l1 = acc[e]; e1 = e; }
    float ex = expf(l1 - l0);
    float inv = 1.f / (1.f + ex);
    tok_e[2*t] = e0; tok_e[2*t+1] = e1;
    tok_p[2*t] = inv; tok_p[2*t+1] = ex * inv;
  }
}

// ---------------- histogram ----------------
__global__ void hist_kernel(const int* __restrict__ tok_e, u32* __restrict__ partial){
  int lane = threadIdx.x & 63;
  int m = blockIdx.x * 64 + lane;
  int e = tok_e[m];
  #pragma unroll
  for (int ee = 0; ee < E_NUM; ee++){
    unsigned long long mk = __ballot(e == ee);
    if (lane == ee) partial[blockIdx.x * E_NUM + ee] = (u32)__popcll(mk);
  }
}

// ---------------- scan + tile table (128-row tiles) ----------------
__global__ void scan_kernel(const u32* __restrict__ partial, u32* __restrict__ baseb,
                            int4* __restrict__ tiles, int* __restrict__ ntiles){
  int lane = threadIdx.x;  // 64 threads
  u32 exc[E_NUM], tot[E_NUM];
  #pragma unroll
  for (int e = 0; e < E_NUM; e++){
    u32 v = partial[lane * E_NUM + e];
    u32 own = v;
    #pragma unroll
    for (int off = 1; off < 64; off <<= 1){
      u32 tu = __shfl_up(v, off, 64);
      if (lane >= off) v += tu;
    }
    exc[e] = v - own;
    tot[e] = __shfl(v, 63, 64);
  }
  u32 offs[E_NUM + 1]; offs[0] = 0;
  #pragma unroll
  for (int e = 0; e < E_NUM; e++) offs[e+1] = offs[e] + tot[e];
  #pragma unroll
  for (int e = 0; e < E_NUM; e++) baseb[lane * E_NUM + e] = offs[e] + exc[e];
  if (lane == 0){
    int nt = 0;
    for (int e = 0; e < E_NUM; e++){
      int cnt = (int)tot[e];
      for (int r0 = 0; r0 < cnt; r0 += 128){
        tiles[nt] = make_int4((int)offs[e] + r0, min(128, cnt - r0), e, 0);
        nt++;
      }
    }
    *ntiles = nt;
  }
}

// ---------------- scatter ----------------
__global__ void scatter_kernel(const int* __restrict__ tok_e, const u32* __restrict__ baseb,
                               int* __restrict__ dest){
  int lane = threadIdx.x & 63;
  int m = blockIdx.x * 64 + lane;
  int e = tok_e[m];
  unsigned long long eq = 0;
  #pragma unroll
  for (int ee = 0; ee < E_NUM; ee++){
    unsigned long long mk = __ballot(e == ee);
    if (e == ee) eq = mk;
  }
  u32 rank = (u32)__popcll(eq & ((1ull << lane) - 1ull));
  dest[m] = (int)(baseb[blockIdx.x * E_NUM + e] + rank);
}

// ---------------- gather x rows -> grouped bf16 ----------------
__global__ __launch_bounds__(256) void gather_kernel(const float* __restrict__ x,
                                                     const int* __restrict__ dest,
                                                     u16* __restrict__ xg){
  int m = blockIdx.x;
  int d = dest[m];
  const float4* xr = (const float4*)(x + (size_t)(m >> 1) * H_DIM);
  float4 v = xr[threadIdx.x];
  ushort4 o;
  o.x = f2bf(v.x); o.y = f2bf(v.y); o.z = f2bf(v.z); o.w = f2bf(v.w);
  ((ushort4*)(xg + (size_t)d * H_DIM))[threadIdx.x] = o;
}

// ---------------- transpose + fp32->bf16: [E][R][C] -> [E][C][R] ----------------
template<int R, int C>
__global__ __launch_bounds__(256) void transpose_cvt(const float* __restrict__ in,
                                                     u16* __restrict__ out){
  int e = blockIdx.z;
  const float* ip = in + (size_t)e * R * C;
  u16* op = out + (size_t)e * R * C;
  __shared__ u16 tile[64][66];
  int c0 = blockIdx.x * 64, r0 = blockIdx.y * 64;
  int tr = threadIdx.x >> 4, tc = threadIdx.x & 15;
  #pragma unroll
  for (int i = 0; i < 4; i++){
    int r = tr + i * 16;
    float4 v = *(const float4*)(ip + (size_t)(r0 + r) * C + c0 + tc * 4);
    tile[r][tc*4+0] = f2bf(v.x); tile[r][tc*4+1] = f2bf(v.y);
    tile[r][tc*4+2] = f2bf(v.z); tile[r][tc*4+3] = f2bf(v.w);
  }
  __syncthreads();
  #pragma unroll
  for (int i = 0; i < 4; i++){
    int c = tr + i * 16;
    ushort4 o;
    o.x = tile[tc*4+0][c]; o.y = tile[tc*4+1][c];
    o.z = tile[tc*4+2][c]; o.w = tile[tc*4+3][c];
    *(ushort4*)(op + (size_t)(c0 + c) * R + r0 + tc * 4) = o;
  }
}

// ---------------- grouped GEMM, m97 structure ----------------
// 128x128 tile, BK=64, 256 threads (4 waves 2x2), 32 KB LDS, 3 blocks/CU.
// A [*][KSTRIDE] bf16 row-major; Bt [E][N][KSTRIDE] bf16 (K-contiguous).
// LDS tiles [128 rows][64 u16] with XOR swizzle: logical (row,kbyte) stored at
// byte row*128 + (kbyte ^ ((row&7)<<4)). Stage writes are linear in lane order
// (gload_lds dest = uniform base + lane*16); the global SOURCE address is
// inverse-swizzled so logical layout matches (rule #21).
template<int N, int KSTRIDE, int NT, bool GELU_EP>
__global__ __launch_bounds__(256, 3) void gemm97(
    const u16* __restrict__ A, const u16* __restrict__ Bt,
    const int4* __restrict__ tiles, const int* __restrict__ ntiles_p,
    float* __restrict__ outF, u16* __restrict__ outB, size_t zstride){
  if ((int)blockIdx.y >= *ntiles_p) return;
  int4 ti = tiles[blockIdx.y];
  int row0 = ti.x, nrows = ti.y, e = ti.z;
  int col0 = blockIdx.x * 128;
  size_t kofs = (size_t)blockIdx.z * ((size_t)NT * 64);
  const u16* Be = Bt + (size_t)e * N * KSTRIDE;
  float* outFz = outF + (size_t)blockIdx.z * zstride;

  __shared__ __align__(16) u16 As[128 * 64];
  __shared__ __align__(16) u16 Bs[128 * 64];
  int lane = threadIdx.x & 63, wid = threadIdx.x >> 6;
  int wr = wid >> 1, wc = wid & 1;

  f32x4 acc[4][4];
  #pragma unroll
  for (int m = 0; m < 4; m++)
    #pragma unroll
    for (int n = 0; n < 4; n++) acc[m][n] = (f32x4)0.f;

  // per-lane constant source swizzle: row%8 == lane>>3 for every chunk/wave
  int srow = (wid << 3) + (lane >> 3);             // row within 32-row chunk grid
  int skx  = ((lane & 7) * 16) ^ ((lane >> 3) << 4);

  for (int kt = 0; kt < NT; kt++){
    size_t kb = kofs + (size_t)kt * 64;
    #pragma unroll
    for (int i = 0; i < 4; i++){
      int row = i * 32 + srow;
      gload_lds16((const char*)(A  + (size_t)(row0 + row) * KSTRIDE + kb) + skx,
                  As + i * 2048 + wid * 512);
      gload_lds16((const char*)(Be + (size_t)(col0 + row) * KSTRIDE + kb) + skx,
                  Bs + i * 2048 + wid * 512);
    }
    __syncthreads();
    short8 a[4][2], b[4][2];
    #pragma unroll
    for (int m = 0; m < 4; m++){
      int row = wr * 64 + m * 16 + (lane & 15);
      #pragma unroll
      for (int kk = 0; kk < 2; kk++){
        int byte_ = row * 128 + ((kk * 64 + (lane >> 4) * 16) ^ ((row & 7) << 4));
        a[m][kk] = *(const short8*)((const char*)As + byte_);
      }
    }
    #pragma unroll
    for (int n = 0; n < 4; n++){
      int row = wc * 64 + n * 16 + (lane & 15);
      #pragma unroll
      for (int kk = 0; kk < 2; kk++){
        int byte_ = row * 128 + ((kk * 64 + (lane >> 4) * 16) ^ ((row & 7) << 4));
        b[n][kk] = *(const short8*)((const char*)Bs + byte_);
      }
    }
    #pragma unroll
    for (int m = 0; m < 4; m++)
      #pragma unroll
      for (int n = 0; n < 4; n++)
        #pragma unroll
        for (int kk = 0; kk < 2; kk++)
          acc[m][n] = __builtin_amdgcn_mfma_f32_16x16x32_bf16(a[m][kk], b[n][kk], acc[m][n], 0, 0, 0);
    __syncthreads();
  }

  #pragma unroll
  for (int m = 0; m < 4; m++){
    int rloc = wr * 64 + m * 16 + (lane >> 4) * 4;
    #pragma unroll
    for (int j = 0; j < 4; j++){
      int rr = rloc + j;
      if (rr < nrows){
        size_t rowg = (size_t)(row0 + rr);
        #pragma unroll
        for (int n = 0; n < 4; n++){
          int cc = col0 + wc * 64 + n * 16 + (lane & 15);
          float v = acc[m][n][j];
          if (GELU_EP){
            float g = v * 0.5f * (1.f + erff(v * 0.70710678118f));
            outFz[rowg * N + cc] = g;
            outB[rowg * N + cc] = f2bf(g);
          } else {
            outFz[rowg * N + cc] = v;
          }
        }
      }
    }
  }
}

// ---------------- combine: sum KSPLIT partials, weighted ----------------
__global__ __launch_bounds__(256) void combine_kernel(const float* __restrict__ yp,
                                                      const int* __restrict__ dest,
                                                      const float* __restrict__ tok_p,
                                                      float* __restrict__ out){
  int t = blockIdx.x;
  int d0 = dest[2*t], d1 = dest[2*t+1];
  float p0 = tok_p[2*t], p1 = tok_p[2*t+1];
  float4 r; r.x = 0.f; r.y = 0.f; r.z = 0.f; r.w = 0.f;
  #pragma unroll
  for (int s = 0; s < KSPLIT; s++){
    float4 a = ((const float4*)(yp + ((size_t)s * M_SLOT + d0) * H_DIM))[threadIdx.x];
    float4 b = ((const float4*)(yp + ((size_t)s * M_SLOT + d1) * H_DIM))[threadIdx.x];
    r.x += p0*a.x + p1*b.x; r.y += p0*a.y + p1*b.y;
    r.z += p0*a.z + p1*b.z; r.w += p0*a.w + p1*b.w;
  }
  ((float4*)(out + (size_t)t * H_DIM))[threadIdx.x] = r;
}

extern "C" void kernel_launch(void* const* d_in, const int* in_sizes, int n_in,
                              void* d_out, int out_size, void* d_ws, size_t ws_size,
                              hipStream_t stream) {
  const float* x  = (const float*)d_in[0];
  const float* rw = (const float*)d_in[1];
  const float* w1 = (const float*)d_in[2];
  const float* w2 = (const float*)d_in[3];
  float* out_mlp  = (float*)d_out;
  float* out_gelu = (float*)d_out + (size_t)T_TOK * H_DIM;

  char* ws = (char*)d_ws;
  // ypart aliases w1t (w1t dead after GEMM1; ypart written by GEMM2)
  u16*   w1t   = (u16*)(ws + 0);                 // [E][F][H] bf16, 64 MB
  float* ypart = (float*)(ws + 0);               // [2][M][H] f32,  32 MB (alias)
  u16*   w2t   = (u16*)(ws + 67108864);          // [E][H][F] bf16, 64 MB
  u16*   xg    = (u16*)(ws + 134217728);         // [M+128][H] bf16
  u16*   gb    = (u16*)(ws + 143130624);         // [M+128][F] bf16
  char*  small = ws + 178782208;
  int*   tok_e = (int*)(small);
  float* tok_p = (float*)(small + 16384);
  int*   dest  = (int*)(small + 32768);
  u32*   partial = (u32*)(small + 49152);
  u32*   baseb   = (u32*)(small + 51200);
  int4*  tiles   = (int4*)(small + 53248);
  int*   ntiles  = (int*)(small + 54272);

  router_kernel<<<T_TOK/4, 256, 0, stream>>>(x, rw, tok_e, tok_p);
  hist_kernel<<<M_SLOT/64, 64, 0, stream>>>(tok_e, partial);
  scan_kernel<<<1, 64, 0, stream>>>(partial, baseb, tiles, ntiles);
  scatter_kernel<<<M_SLOT/64, 64, 0, stream>>>(tok_e, baseb, dest);
  gather_kernel<<<M_SLOT, 256, 0, stream>>>(x, dest, xg);
  transpose_cvt<H_DIM, F_DIM><<<dim3(F_DIM/64, H_DIM/64, E_NUM), 256, 0, stream>>>(w1, w1t);
  transpose_cvt<F_DIM, H_DIM><<<dim3(H_DIM/64, F_DIM/64, E_NUM), 256, 0, stream>>>(w2, w2t);
  // GEMM1: [M,1024] @ [1024,4096] + GELU -> out_gelu (f32) + gb (bf16)
  gemm97<F_DIM, H_DIM, 16, true><<<dim3(F_DIM/128, MAXTILES, 1), 256, 0, stream>>>(
      xg, w1t, tiles, ntiles, out_gelu, gb, 0);
  // GEMM2: [M,4096] @ [4096,1024], split-K=2 -> ypart
  gemm97<H_DIM, F_DIM, 32, false><<<dim3(H_DIM/128, MAXTILES, KSPLIT), 256, 0, stream>>>(
      gb, w2t, tiles, ntiles, ypart, nullptr, (size_t)M_SLOT * H_DIM);
  combine_kernel<<<T_TOK, 256, 0, stream>>>(ypart, dest, tok_p, out_mlp);
}